// Round 1
// baseline (30158.463 us; speedup 1.0000x reference)
//
#include <hip/hip_runtime.h>
#include <hip/hip_cooperative_groups.h>

namespace cg = cooperative_groups;

#define HID   512
#define BATCH 256
#define SEQ   512
#define UPB   8        // hidden units per block
#define GR    32       // gate rows per block = 4*UPB
#define NBPL  64       // blocks per layer
#define NBLK  192
#define NTHR  512

typedef __attribute__((ext_vector_type(8))) _Float16 half8;
typedef __attribute__((ext_vector_type(16))) float f32x16;

__device__ __forceinline__ float sigf(float x) {
  return 1.0f / (1.0f + __expf(-x));
}

__global__ __launch_bounds__(NTHR, 2)
void lstm3_persistent(const float* __restrict__ tracks,
                      const float* __restrict__ Wih0, const float* __restrict__ bih0,
                      const float* __restrict__ Whh0, const float* __restrict__ bhh0,
                      const float* __restrict__ Wih1, const float* __restrict__ bih1,
                      const float* __restrict__ Whh1, const float* __restrict__ bhh1,
                      const float* __restrict__ Wih2, const float* __restrict__ bih2,
                      const float* __restrict__ Whh2, const float* __restrict__ bhh2,
                      const float* __restrict__ Wpred, const float* __restrict__ bpred,
                      float* __restrict__ out, unsigned short* __restrict__ ws)
{
  // 64 KiB static LDS: [mat 0=W_ih slice | mat 1=W_hh slice], fp16, XOR-swizzled
  __shared__ _Float16 sW[2 * GR * 512];

  const int blk   = blockIdx.x;
  const int layer = blk / NBPL;           // 0,1,2
  const int nb    = blk - layer * NBPL;
  const int u0    = nb * UPB;             // first hidden unit owned by this block
  const int tid   = threadIdx.x;
  const int lane  = tid & 63;
  const int wave  = tid >> 6;

  const float* Wih = (layer == 0) ? Wih0 : (layer == 1 ? Wih1 : Wih2);
  const float* Whh = (layer == 0) ? Whh0 : (layer == 1 ? Whh1 : Whh2);
  const float* bih = (layer == 0) ? bih0 : (layer == 1 ? bih1 : bih2);
  const float* bhh = (layer == 0) ? bhh0 : (layer == 1 ? bhh1 : bhh2);

  // ---- stage weight slices into LDS (once) ----
  // LDS row r = gate_type*8 + unit  <->  global gate row = gate_type*512 + u0 + unit
  for (int mat = 0; mat < 2; ++mat) {
    if (layer == 0 && mat == 0) continue;   // layer-0 input GEMM (K=2) handled in VALU
    const float* src = (mat == 0) ? Wih : Whh;
    for (int i = tid; i < GR * 512; i += NTHR) {
      const int r = i >> 9;
      const int k = i & 511;
      const int grow = (r >> 3) * HID + u0 + (r & 7);
      const int g = (k >> 3) ^ (r & 7);     // 16B-granule swizzle vs bank conflicts
      sW[mat * (GR * 512) + r * 512 + g * 8 + (k & 7)] = (_Float16)src[grow * 512 + k];
    }
  }

  // ---- per-lane elementwise constants ----
  const int c  = lane & 31;      // acc column = LDS gate row
  const int tg = c >> 3;         // gate type 0..3 = i,f,g,o
  const int uu = c & 7;          // unit within block
  const int grow_c = tg * HID + u0 + uu;
  const float bias_c = bih[grow_c] + bhh[grow_c];
  float w0_c = 0.f, w1_c = 0.f;
  if (layer == 0) { w0_c = Wih0[grow_c * 2]; w1_c = Wih0[grow_c * 2 + 1]; }

  // c-state: 16 batch rows per lane (4x redundant across gate-type lane groups)
  float cst[16];
  #pragma unroll
  for (int r = 0; r < 16; ++r) cst[r] = 0.f;

  _Float16* hws  = (_Float16*)ws;   // 12 arrays: [layer][parity][hi/lo][BATCH][HID]
  const int brow = wave * 32 + (lane & 31);
  const int hi2  = lane >> 5;
  const int rb   = (lane & 31) * 64;    // half8-units row base in sW
  const int rx   = (lane & 31) & 7;
  const half8* bp = (const half8*)sW;

  cg::grid_group grid = cg::this_grid();
  __syncthreads();   // LDS weights ready (block-local dependency only)

  for (int u = 0; u < SEQ + 2; ++u) {
    const int t = u - layer;
    if (t >= 0 && t < SEQ) {
      const int pr = (u + 1) & 1;   // read parity (written last tick / zero-init)
      const int pw = u & 1;         // write parity

      f32x16 acc;
      #pragma unroll
      for (int r = 0; r < 16; ++r) acc[r] = 0.f;

      if (layer > 0) {  // input GEMM: x = h_{layer-1}[t]
        const _Float16* Ahi = hws + (size_t)(((layer - 1) * 2 + pr) * 2 + 0) * (BATCH * HID);
        const _Float16* Alo = hws + (size_t)(((layer - 1) * 2 + pr) * 2 + 1) * (BATCH * HID);
        const half8* ah = (const half8*)(Ahi + brow * HID);
        const half8* al = (const half8*)(Alo + brow * HID);
        #pragma unroll 4
        for (int ks = 0; ks < 32; ++ks) {
          const int gi = ks * 2 + hi2;
          half8 av = ah[gi];
          half8 lv = al[gi];
          half8 bv = bp[rb + (gi ^ rx)];                          // mat 0 = W_ih
          acc = __builtin_amdgcn_mfma_f32_32x32x16_f16(av, bv, acc, 0, 0, 0);
          acc = __builtin_amdgcn_mfma_f32_32x32x16_f16(lv, bv, acc, 0, 0, 0);
        }
      }
      {  // hidden GEMM: h_prev = h_layer[t-1]
        const _Float16* Ahi = hws + (size_t)((layer * 2 + pr) * 2 + 0) * (BATCH * HID);
        const _Float16* Alo = hws + (size_t)((layer * 2 + pr) * 2 + 1) * (BATCH * HID);
        const half8* ah = (const half8*)(Ahi + brow * HID);
        const half8* al = (const half8*)(Alo + brow * HID);
        #pragma unroll 4
        for (int ks = 0; ks < 32; ++ks) {
          const int gi = ks * 2 + hi2;
          half8 av = ah[gi];
          half8 lv = al[gi];
          half8 bv = bp[2048 + rb + (gi ^ rx)];                   // mat 1 = W_hh
          acc = __builtin_amdgcn_mfma_f32_32x32x16_f16(av, bv, acc, 0, 0, 0);
          acc = __builtin_amdgcn_mfma_f32_32x32x16_f16(lv, bv, acc, 0, 0, 0);
        }
      }

      // ---- elementwise: bias + (layer-0 K=2 input) then gate nonlinearities ----
      float gv[16];
      #pragma unroll
      for (int r = 0; r < 16; ++r) {
        float g = acc[r] + bias_c;
        if (layer == 0) {
          const int m = (r & 3) + 8 * (r >> 2) + 4 * hi2 + 32 * wave;
          const float2* xp = (const float2*)tracks;
          const float2 xv = xp[(size_t)m * SEQ + t];
          g += w0_c * xv.x + w1_c * xv.y;
        }
        gv[r] = g;
      }

      const int sb = (lane & 32) | uu;   // gather i,f,g,o for unit uu (same half-wave)
      _Float16* Ohi = hws + (size_t)((layer * 2 + pw) * 2 + 0) * (BATCH * HID);
      _Float16* Olo = hws + (size_t)((layer * 2 + pw) * 2 + 1) * (BATCH * HID);
      #pragma unroll
      for (int r = 0; r < 16; ++r) {
        const float gi_ = __shfl(gv[r], sb,      64);
        const float gf_ = __shfl(gv[r], sb | 8,  64);
        const float gg_ = __shfl(gv[r], sb | 16, 64);
        const float go_ = __shfl(gv[r], sb | 24, 64);
        const float iv = sigf(gi_);
        const float fv = sigf(gf_);
        const float gn = tanhf(gg_);
        const float ov = sigf(go_);
        const float cn = fv * cst[r] + iv * gn;
        cst[r] = cn;
        const float hn = ov * tanhf(cn);
        if ((r >> 2) == tg) {  // each gate-type lane group stores its row-quad
          const int m = (r & 3) + 8 * tg + 4 * hi2 + 32 * wave;
          const _Float16 hif = (_Float16)hn;
          const _Float16 lof = (_Float16)(hn - (float)hif);
          Ohi[(size_t)m * HID + u0 + uu] = hif;
          Olo[(size_t)m * HID + u0 + uu] = lof;
        }
      }
    }
    grid.sync();
  }

  // ---- output head: out[b][p] = elu(h2_final[b]) . Wpred[p] + bpred[p] ----
  // final h2 written at tick 513 -> parity 1
  const int gw = blk * 8 + wave;
  if (gw < BATCH * 4) {
    const int b = gw >> 2;
    const int p = gw & 3;
    const _Float16* Hhi = hws + (size_t)((2 * 2 + 1) * 2 + 0) * (BATCH * HID);
    const _Float16* Hlo = hws + (size_t)((2 * 2 + 1) * 2 + 1) * (BATCH * HID);
    const int k = lane * 8;
    float a = 0.f;
    #pragma unroll
    for (int j = 0; j < 8; ++j) {
      const float hv = (float)Hhi[(size_t)b * HID + k + j] + (float)Hlo[(size_t)b * HID + k + j];
      const float e = hv > 0.f ? hv : expm1f(hv);
      a += e * Wpred[p * HID + k + j];
    }
    #pragma unroll
    for (int off = 32; off > 0; off >>= 1) a += __shfl_down(a, off, 64);
    if (lane == 0) out[b * 4 + p] = a + bpred[p];
  }
}

extern "C" void kernel_launch(void* const* d_in, const int* in_sizes, int n_in,
                              void* d_out, int out_size, void* d_ws, size_t ws_size,
                              hipStream_t stream) {
  const float* tracks = (const float*)d_in[0];
  const float* Wih0  = (const float*)d_in[1];
  const float* bih0  = (const float*)d_in[2];
  const float* Whh0  = (const float*)d_in[3];
  const float* bhh0  = (const float*)d_in[4];
  const float* Wih1  = (const float*)d_in[5];
  const float* bih1  = (const float*)d_in[6];
  const float* Whh1  = (const float*)d_in[7];
  const float* bhh1  = (const float*)d_in[8];
  const float* Wih2  = (const float*)d_in[9];
  const float* bih2  = (const float*)d_in[10];
  const float* Whh2  = (const float*)d_in[11];
  const float* bhh2  = (const float*)d_in[12];
  const float* Wpred = (const float*)d_in[13];
  const float* bpred = (const float*)d_in[14];
  float* out = (float*)d_out;
  unsigned short* ws = (unsigned short*)d_ws;

  // zero the h double-buffers every call (harness poisons ws once; recurrence
  // must start from h=0 deterministically on every replay)
  hipMemsetAsync(d_ws, 0, (size_t)12 * BATCH * HID * sizeof(unsigned short), stream);

  void* args[] = { &tracks, &Wih0, &bih0, &Whh0, &bhh0,
                   &Wih1, &bih1, &Whh1, &bhh1,
                   &Wih2, &bih2, &Whh2, &bhh2,
                   &Wpred, &bpred, &out, &ws };
  hipLaunchCooperativeKernel(reinterpret_cast<void*>(lstm3_persistent),
                             dim3(NBLK), dim3(NTHR), args, 0, stream);
}

// Round 2
// 20364.302 us; speedup vs baseline: 1.4809x; 1.4809x over previous
//
#include <hip/hip_runtime.h>
#include <hip/hip_cooperative_groups.h>

namespace cg = cooperative_groups;

#define HID   512
#define BATCH 256
#define SEQ   512
#define UPB   16       // hidden units per block
#define GR    64       // gate rows per block = 4*UPB
#define NBLK  192
#define NTHR  512
// per-(layer,parity) h array: 8 rowblk x 64 gran x 2 hilo x 32 lane x 8 halves
#define HARR  262144   // halfwords = BATCH*HID*2

typedef __attribute__((ext_vector_type(8))) _Float16 half8;
typedef __attribute__((ext_vector_type(16))) float f32x16;

__device__ __forceinline__ float sigf(float x) {
  return 1.0f / (1.0f + __expf(-x));
}

__global__ __launch_bounds__(NTHR, 2)
void lstm3_persistent(const float* __restrict__ tracks,
                      const float* __restrict__ Wih0, const float* __restrict__ bih0,
                      const float* __restrict__ Whh0, const float* __restrict__ bhh0,
                      const float* __restrict__ Wih1, const float* __restrict__ bih1,
                      const float* __restrict__ Whh1, const float* __restrict__ bhh1,
                      const float* __restrict__ Wih2, const float* __restrict__ bih2,
                      const float* __restrict__ Whh2, const float* __restrict__ bhh2,
                      const float* __restrict__ Wpred, const float* __restrict__ bpred,
                      float* __restrict__ out, unsigned short* __restrict__ ws)
{
  // 128 KiB dynamic LDS: [mat 0=W_ih slice | mat 1=W_hh slice], fp16, XOR-swizzled
  extern __shared__ _Float16 sW[];

  const int blk   = blockIdx.x;
  const int layer = blk / 64;             // 0,1,2
  const int nb    = blk - layer * 64;
  const int ug    = nb >> 1;              // unit group 0..31
  const int bh    = nb & 1;               // batch half 0..1
  const int u0    = ug * UPB;             // first hidden unit owned by this block
  const int tid   = threadIdx.x;
  const int lane  = tid & 63;
  const int wave  = tid >> 6;
  const int gr32  = wave & 1;             // which 32 of the 64 gate rows
  const int bq    = wave >> 1;            // which 32-batch quarter of the 128
  const int lane32 = lane & 31;
  const int hi2   = lane >> 5;
  const int rowblk = bh * 4 + bq;         // global 32-row batch block 0..7

  const float* Wih = (layer == 0) ? Wih0 : (layer == 1 ? Wih1 : Wih2);
  const float* Whh = (layer == 0) ? Whh0 : (layer == 1 ? Whh1 : Whh2);
  const float* bih = (layer == 0) ? bih0 : (layer == 1 ? bih1 : bih2);
  const float* bhh = (layer == 0) ? bhh0 : (layer == 1 ? bhh1 : bhh2);

  // ---- stage weight slices into LDS (once) ----
  // LDS row r = uu*4 + tg  <->  global gate row = tg*512 + u0 + uu
  for (int mat = 0; mat < 2; ++mat) {
    if (layer == 0 && mat == 0) continue;   // layer-0 input GEMM (K=2) handled in VALU
    const float* src = (mat == 0) ? Wih : Whh;
    for (int i = tid; i < GR * 512; i += NTHR) {
      const int r = i >> 9;
      const int k = i & 511;
      const int grow = (r & 3) * HID + u0 + (r >> 2);
      const int g = (k >> 3) ^ (r & 7);     // 16B-granule swizzle vs bank conflicts
      sW[mat * (GR * 512) + r * 512 + g * 8 + (k & 7)] = (_Float16)src[grow * 512 + k];
    }
  }

  // ---- per-lane elementwise constants ----
  const int c   = lane32;                 // acc column within wave tile
  const int r64 = gr32 * 32 + c;          // LDS gate row
  const int tg  = r64 & 3;                // gate type 0..3 = i,f,g,o
  const int uu  = r64 >> 2;               // unit within block 0..15
  const int grow_c = tg * HID + u0 + uu;
  const float bias_c = bih[grow_c] + bhh[grow_c];
  float w0_c = 0.f, w1_c = 0.f;
  if (layer == 0) { w0_c = Wih0[grow_c * 2]; w1_c = Wih0[grow_c * 2 + 1]; }

  // c-state: 16 batch rows per lane (4x redundant across gate-type lanes)
  float cst[16];
  #pragma unroll
  for (int r = 0; r < 16; ++r) cst[r] = 0.f;

  _Float16* hws  = (_Float16*)ws;   // 6 arrays: [layer][parity] of HARR halves
  const half8* bp = (const half8*)sW;
  const int rbase = r64 * 64;       // half8 units per LDS B row
  const int rx    = r64 & 7;
  const int m0    = bh * 128 + bq * 32;   // wave's first batch row

  cg::grid_group grid = cg::this_grid();
  __syncthreads();   // LDS weights ready (block-local dependency only)

  for (int u = 0; u < SEQ + 2; ++u) {
    const int t = u - layer;
    if (t >= 0 && t < SEQ) {
      const int pr = (u + 1) & 1;   // read parity (written last tick / zero-init)
      const int pw = u & 1;         // write parity

      f32x16 acc;
      #pragma unroll
      for (int r = 0; r < 16; ++r) acc[r] = 0.f;

      if (layer > 0) {  // input GEMM: x = h_{layer-1}[t], fragment-major layout
        const half8* ap = (const half8*)(hws + (size_t)((layer - 1) * 2 + pr) * HARR);
        #pragma unroll 8
        for (int ks = 0; ks < 32; ++ks) {
          const int gi = ks * 2 + hi2;
          const int ci = (rowblk * 64 + gi) * 64 + lane32;   // half8 index
          half8 av = ap[ci];
          half8 lv = ap[ci + 32];
          half8 bv = bp[rbase + (gi ^ rx)];                  // mat 0 = W_ih
          acc = __builtin_amdgcn_mfma_f32_32x32x16_f16(av, bv, acc, 0, 0, 0);
          acc = __builtin_amdgcn_mfma_f32_32x32x16_f16(lv, bv, acc, 0, 0, 0);
        }
      }
      {  // hidden GEMM: h_prev = h_layer[t-1]
        const half8* ap = (const half8*)(hws + (size_t)(layer * 2 + pr) * HARR);
        #pragma unroll 8
        for (int ks = 0; ks < 32; ++ks) {
          const int gi = ks * 2 + hi2;
          const int ci = (rowblk * 64 + gi) * 64 + lane32;
          half8 av = ap[ci];
          half8 lv = ap[ci + 32];
          half8 bv = bp[4096 + rbase + (gi ^ rx)];           // mat 1 = W_hh
          acc = __builtin_amdgcn_mfma_f32_32x32x16_f16(av, bv, acc, 0, 0, 0);
          acc = __builtin_amdgcn_mfma_f32_32x32x16_f16(lv, bv, acc, 0, 0, 0);
        }
      }

      // ---- elementwise: bias + (layer-0 K=2 input) then gate nonlinearities ----
      float gv[16];
      #pragma unroll
      for (int r = 0; r < 16; ++r) {
        float g = acc[r] + bias_c;
        if (layer == 0) {
          const int m = m0 + (r & 3) + 8 * (r >> 2) + 4 * hi2;
          const float2* xp = (const float2*)tracks;
          const float2 xv = xp[(size_t)m * SEQ + t];
          g += w0_c * xv.x + w1_c * xv.y;
        }
        gv[r] = g;
      }

      // gather i,f,g,o for unit uu: cols (c&28)+0..3 in same half-wave
      const int sb = (lane & 32) | (c & 28);
      _Float16* wr = hws + (size_t)(layer * 2 + pw) * HARR;
      const int gran = (u0 + uu) >> 3;
      const int k7   = (u0 + uu) & 7;
      #pragma unroll
      for (int r = 0; r < 16; ++r) {
        const float gi_ = __shfl(gv[r], sb,     64);
        const float gf_ = __shfl(gv[r], sb | 1, 64);
        const float gg_ = __shfl(gv[r], sb | 2, 64);
        const float go_ = __shfl(gv[r], sb | 3, 64);
        const float iv = sigf(gi_);
        const float fv = sigf(gf_);
        const float gn = tanhf(gg_);
        const float ov = sigf(go_);
        const float cn = fv * cst[r] + iv * gn;
        cst[r] = cn;
        const float hn = ov * tanhf(cn);
        if ((r >> 2) == tg) {  // each gate-type lane writes its batch-row quad
          const int m_local = (r & 3) + 8 * tg + 4 * hi2;
          const _Float16 hif = (_Float16)hn;
          const _Float16 lof = (_Float16)(hn - (float)hif);
          const int off = (((rowblk * 64 + gran) * 2 + 0) * 32 + m_local) * 8 + k7;
          wr[off]       = hif;
          wr[off + 256] = lof;   // hilo=1 chunk is +32*8 halves
        }
      }
    }
    grid.sync();
  }

  // ---- output head: out[b][p] = elu(h2_final[b]) . Wpred[p] + bpred[p] ----
  // final h2 written at tick 513 -> parity 1
  const int gw = blk * 8 + wave;
  if (gw < BATCH * 4) {
    const int b = gw >> 2;
    const int p = gw & 3;
    const _Float16* Hf = hws + (size_t)(2 * 2 + 1) * HARR;
    const int k = lane * 8;          // gran = lane
    const int offh = ((((b >> 5) * 64 + lane) * 2 + 0) * 32 + (b & 31)) * 8;
    float a = 0.f;
    #pragma unroll
    for (int j = 0; j < 8; ++j) {
      const float hv = (float)Hf[offh + j] + (float)Hf[offh + 256 + j];
      const float e = hv > 0.f ? hv : expm1f(hv);
      a += e * Wpred[p * HID + k + j];
    }
    #pragma unroll
    for (int off = 32; off > 0; off >>= 1) a += __shfl_down(a, off, 64);
    if (lane == 0) out[b * 4 + p] = a + bpred[p];
  }
}

extern "C" void kernel_launch(void* const* d_in, const int* in_sizes, int n_in,
                              void* d_out, int out_size, void* d_ws, size_t ws_size,
                              hipStream_t stream) {
  const float* tracks = (const float*)d_in[0];
  const float* Wih0  = (const float*)d_in[1];
  const float* bih0  = (const float*)d_in[2];
  const float* Whh0  = (const float*)d_in[3];
  const float* bhh0  = (const float*)d_in[4];
  const float* Wih1  = (const float*)d_in[5];
  const float* bih1  = (const float*)d_in[6];
  const float* Whh1  = (const float*)d_in[7];
  const float* bhh1  = (const float*)d_in[8];
  const float* Wih2  = (const float*)d_in[9];
  const float* bih2  = (const float*)d_in[10];
  const float* Whh2  = (const float*)d_in[11];
  const float* bhh2  = (const float*)d_in[12];
  const float* Wpred = (const float*)d_in[13];
  const float* bpred = (const float*)d_in[14];
  float* out = (float*)d_out;
  unsigned short* ws = (unsigned short*)d_ws;

  // allow 128 KiB dynamic LDS (host-side attribute, idempotent, capture-safe)
  hipFuncSetAttribute(reinterpret_cast<const void*>(lstm3_persistent),
                      hipFuncAttributeMaxDynamicSharedMemorySize, 131072);

  // zero the h double-buffers every call (recurrence starts from h=0 on every replay)
  hipMemsetAsync(d_ws, 0, (size_t)6 * HARR * sizeof(unsigned short), stream);

  void* args[] = { &tracks, &Wih0, &bih0, &Whh0, &bhh0,
                   &Wih1, &bih1, &Whh1, &bhh1,
                   &Wih2, &bih2, &Whh2, &bhh2,
                   &Wpred, &bpred, &out, &ws };
  hipLaunchCooperativeKernel(reinterpret_cast<void*>(lstm3_persistent),
                             dim3(NBLK), dim3(NTHR), args, 131072, stream);
}